// Round 10
// baseline (405.408 us; speedup 1.0000x reference)
//
#include <hip/hip_runtime.h>

// FCtL attention fusion for MI355X (gfx950).
// B=1, C=256 (inplanes), P=64 (planes), H=W=96 -> N=M=9216.
//
// R7 k4 restructure (from rocprof: MfmaUtil 8.6%, Occ 14%, latency-bound on
// stage->barrier->compute serialization at 2 blocks/CU):
//   - K LDS staging removed: K fragments loaded per-wave from global (L2-hot).
//   - V staged via register prefetch (T14 async-STAGE): load t+1 into regs
//     during compute of t, commit to LDS after the barrier.
//   - LDS 55->45 KB -> 3 blocks/CU (__launch_bounds__(256,3), VGPR cap 170).
//
// MFMA 16x16x32 bf16 layouts (learn_hip verified):
//   A: row = lane&15,  k = (lane>>4)*8 + i   (8 contig bf16)
//   B: col = lane&15,  k = (lane>>4)*8 + i
//   C/D: col = lane&15, row = (lane>>4)*4 + reg

typedef __attribute__((ext_vector_type(8))) short short8;
typedef __attribute__((ext_vector_type(8))) unsigned short ushort8;
typedef __attribute__((ext_vector_type(4))) float f32x4;

#define C_DIM 256
#define P_DIM 64
#define N_DIM 9216
#define NT    144     // n-tiles of 64
#define SPLITS 4
#define MQ    (N_DIM / SPLITS)   // 2304
#define KV_TILES (MQ / 64)       // 36

__device__ __forceinline__ unsigned short f2b(float f) {
  unsigned int u = __float_as_uint(f);
  u += 0x7fffu + ((u >> 16) & 1u);   // RNE (finite values only)
  return (unsigned short)(u >> 16);
}

__device__ __forceinline__ float b2f(unsigned short h) {
  return __uint_as_float(((unsigned int)h) << 16);
}

__device__ __forceinline__ f32x4 mfma16(short8 a, short8 b, f32x4 c) {
  return __builtin_amdgcn_mfma_f32_16x16x32_bf16(a, b, c, 0, 0, 0);
}

// ---------------- k1: means + bf16 conversion ----------------
__global__ void k1_mean_conv(const float* __restrict__ x, const float* __restrict__ y,
                             unsigned short* __restrict__ xb, unsigned short* __restrict__ yb,
                             float* __restrict__ xmean, float* __restrict__ ymean) {
  int b = blockIdx.x;
  const float* src = (b < C_DIM) ? x : y;
  unsigned short* dst = (b < C_DIM) ? xb : yb;
  float* mout = (b < C_DIM) ? xmean : ymean;
  int c = b & (C_DIM - 1);
  const float4* row = (const float4*)(src + (size_t)c * N_DIM);
  ushort4* orow = (ushort4*)(dst + (size_t)c * N_DIM);
  int tid = threadIdx.x;
  float s = 0.f;
  for (int i = tid; i < N_DIM / 4; i += 256) {
    float4 v = row[i];
    s += v.x + v.y + v.z + v.w;
    ushort4 o;
    o.x = f2b(v.x); o.y = f2b(v.y); o.z = f2b(v.z); o.w = f2b(v.w);
    orow[i] = o;
  }
#pragma unroll
  for (int off = 1; off < 64; off <<= 1) s += __shfl_xor(s, off);
  __shared__ float red[4];
  if ((tid & 63) == 0) red[tid >> 6] = s;
  __syncthreads();
  if (tid == 0) mout[c] = (red[0] + red[1] + red[2] + red[3]) * (1.f / (float)N_DIM);
}

// ---------------- k2: weight conversion + projected means ----------------
__global__ void k2_wconv(const float* __restrict__ Wv, const float* __restrict__ Wq,
                         const float* __restrict__ Wk,
                         const float* __restrict__ xmean, const float* __restrict__ ymean,
                         unsigned short* __restrict__ Wvb, unsigned short* __restrict__ Wqb,
                         unsigned short* __restrict__ Wkb,
                         float* __restrict__ qmean, float* __restrict__ kmean) {
  int b = blockIdx.x, t = threadIdx.x;
  if (b < 256) {
    int i = b * 256 + t; Wvb[i] = f2b(Wv[i]);
  } else if (b < 320) {
    int i = (b - 256) * 256 + t; Wqb[i] = f2b(Wq[i]);
  } else if (b < 384) {
    int i = (b - 320) * 256 + t; Wkb[i] = f2b(Wk[i]);
  } else if (t < 128) {
    // qmean[p] = Wq[p,:] . xmean   (bias cancels in centering)
    int p = t & 63;
    const float* W = (t < 64) ? Wq : Wk;
    const float* mv = (t < 64) ? xmean : ymean;
    float s = 0.f;
    for (int cc = 0; cc < 256; cc++) s += W[p * 256 + cc] * mv[cc];
    ((t < 64) ? qmean : kmean)[p] = s;
  }
}

// ---------------- k3: MFMA projections ----------------
// blocks 0..143: V-tile (V[c][m]); 144..287: Q-tile (Q[n][p]); 288..431: K-tile
__global__ void k3_proj(const unsigned short* __restrict__ xb, const unsigned short* __restrict__ yb,
                        const unsigned short* __restrict__ Wvb, const unsigned short* __restrict__ Wqb,
                        const unsigned short* __restrict__ Wkb,
                        const float* __restrict__ qmean, const float* __restrict__ kmean,
                        unsigned short* __restrict__ Qb, unsigned short* __restrict__ Kb,
                        unsigned short* __restrict__ Vb) {
  __shared__ unsigned short T[64][264];  // transposed input tile [m/n][c]
  int b = blockIdx.x;
  int role = b / NT;       // 0=V 1=Q 2=K
  int tile = b % NT;
  int m0 = tile * 64;
  int tid = threadIdx.x;
  int w = tid >> 6, lane = tid & 63, l16 = lane & 15, g4 = lane >> 4;

  const unsigned short* src = (role == 1) ? xb : yb;
  {
    int c = tid;  // 256 threads = 256 channels
    const unsigned short* sr = src + (size_t)c * N_DIM + m0;
#pragma unroll
    for (int j = 0; j < 8; j++) {
      ushort8 v = *(const ushort8*)&sr[j * 8];
#pragma unroll
      for (int i = 0; i < 8; i++) T[j * 8 + i][c] = v[i];
    }
  }
  __syncthreads();

  if (role == 0) {
    // rows = c_out (wave owns 64), cols = m (64), k = c_in (256)
    f32x4 acc[4][4];
#pragma unroll
    for (int rf = 0; rf < 4; rf++)
#pragma unroll
      for (int cf = 0; cf < 4; cf++) acc[rf][cf] = (f32x4)0.f;
#pragma unroll
    for (int kk = 0; kk < 8; kk++) {
      short8 bf[4];
#pragma unroll
      for (int cf = 0; cf < 4; cf++)
        bf[cf] = *(const short8*)&T[cf * 16 + l16][kk * 32 + g4 * 8];
#pragma unroll
      for (int rf = 0; rf < 4; rf++) {
        short8 af = *(const short8*)&Wvb[(size_t)(w * 64 + rf * 16 + l16) * 256 + kk * 32 + g4 * 8];
#pragma unroll
        for (int cf = 0; cf < 4; cf++) acc[rf][cf] = mfma16(af, bf[cf], acc[rf][cf]);
      }
    }
#pragma unroll
    for (int rf = 0; rf < 4; rf++)
#pragma unroll
      for (int cf = 0; cf < 4; cf++)
#pragma unroll
        for (int r = 0; r < 4; r++) {
          int co = w * 64 + rf * 16 + g4 * 4 + r;
          int m = m0 + cf * 16 + l16;
          Vb[(size_t)co * N_DIM + m] = f2b(acc[rf][cf][r]);
        }
  } else {
    const unsigned short* Wb = (role == 1) ? Wqb : Wkb;
    const float* mean = (role == 1) ? qmean : kmean;
    unsigned short* Ob = (role == 1) ? Qb : Kb;
    // rows = n (wave owns 16), cols = p (64), k = c (256)
    f32x4 acc[4];
#pragma unroll
    for (int cf = 0; cf < 4; cf++) acc[cf] = (f32x4)0.f;
#pragma unroll
    for (int kk = 0; kk < 8; kk++) {
      short8 af = *(const short8*)&T[w * 16 + l16][kk * 32 + g4 * 8];
#pragma unroll
      for (int cf = 0; cf < 4; cf++) {
        short8 bf = *(const short8*)&Wb[(size_t)(cf * 16 + l16) * 256 + kk * 32 + g4 * 8];
        acc[cf] = mfma16(af, bf, acc[cf]);
      }
    }
#pragma unroll
    for (int cf = 0; cf < 4; cf++)
#pragma unroll
      for (int r = 0; r < 4; r++) {
        int n = m0 + w * 16 + g4 * 4 + r;
        int p = cf * 16 + l16;
        Ob[(size_t)n * 64 + p] = f2b(acc[cf][r] - mean[p]);
      }
  }
}

// ---------------- k4: flash attention (wave-owns-rows, async V-stage) ----------------
// grid 576: b&3 = M-split, b>>2 = n-tile. 4 waves; wave w owns Q-rows
// [n0+w*16, n0+w*16+16) across the FULL m extent.
// K fragments direct from global (L2-hot). V reg-prefetched -> LDS.
__global__ __launch_bounds__(256, 3)
void k4_attn(const unsigned short* __restrict__ Qb, const unsigned short* __restrict__ Kb,
             const unsigned short* __restrict__ Vb,
             unsigned short* __restrict__ po, float* __restrict__ m_arr, float* __restrict__ l_arr) {
  __shared__ unsigned short Vt[256][72];
  __shared__ unsigned short Pt[64][72];   // wave-private 16-row strips

  int b = blockIdx.x;
  int s = b & (SPLITS - 1);
  int n0 = (b >> 2) * 64;
  int tid = threadIdx.x;
  int w = tid >> 6, lane = tid & 63, l16 = lane & 15, g4 = lane >> 4;

  // Q A-fragments straight from global: row = l16 -> n = n0 + w*16 + l16
  short8 qf[2];
  {
    const unsigned short* qrow = Qb + (size_t)(n0 + w * 16 + l16) * 64;
    qf[0] = *(const short8*)&qrow[g4 * 8];
    qf[1] = *(const short8*)&qrow[32 + g4 * 8];
  }

  f32x4 acc[16];                 // O strip: rows n (g4*4+r), cols c = cfc*16+l16
#pragma unroll
  for (int i = 0; i < 16; i++) acc[i] = (f32x4)0.f;
  float mreg[4], lreg[4];        // per-lane copies for rows n = g4*4 + r
#pragma unroll
  for (int r = 0; r < 4; r++) { mreg[r] = -3e38f; lreg[r] = 0.f; }

  int mbase = s * MQ;

  // prefetch V tile 0: thread owns V-row `tid`, 128B contiguous
  ushort8 vreg[8];
  {
    const ushort8* vsrc = (const ushort8*)(Vb + (size_t)tid * N_DIM + mbase);
#pragma unroll
    for (int j = 0; j < 8; j++) vreg[j] = vsrc[j];
  }

  for (int t = 0; t < KV_TILES; t++) {
    int m0 = mbase + t * 64;
    if (t) __syncthreads();          // previous iter's Vt reads complete
#pragma unroll
    for (int j = 0; j < 8; j++) *(ushort8*)&Vt[tid][j * 8] = vreg[j];
    __syncthreads();                 // Vt ready

    // QK^T: S[16n x 64m] per wave; K fragments direct from global.
    f32x4 sa[4];
#pragma unroll
    for (int cf = 0; cf < 4; cf++) sa[cf] = (f32x4)0.f;
#pragma unroll
    for (int kk = 0; kk < 2; kk++) {
#pragma unroll
      for (int cf = 0; cf < 4; cf++) {
        short8 kf = *(const short8*)&Kb[(size_t)(m0 + cf * 16 + l16) * 64 + kk * 32 + g4 * 8];
        sa[cf] = mfma16(qf[kk], kf, sa[cf]);
      }
    }

    // prefetch V tile t+1 (latency hides under softmax + PV)
    if (t + 1 < KV_TILES) {
      const ushort8* vsrc = (const ushort8*)(Vb + (size_t)tid * N_DIM + m0 + 64);
#pragma unroll
      for (int j = 0; j < 8; j++) vreg[j] = vsrc[j];
    }

    // wave-local online softmax (rows r; reduce over cf + 16-lane group)
    float f[4];
#pragma unroll
    for (int r = 0; r < 4; r++) {
      float v = fmaxf(fmaxf(sa[0][r], sa[1][r]), fmaxf(sa[2][r], sa[3][r]));
#pragma unroll
      for (int off = 1; off < 16; off <<= 1) v = fmaxf(v, __shfl_xor(v, off));
      float mnew = fmaxf(mreg[r], v);
      f[r] = __expf(mreg[r] - mnew);
      mreg[r] = mnew;
    }
    // P in place of S
#pragma unroll
    for (int cf = 0; cf < 4; cf++)
#pragma unroll
      for (int r = 0; r < 4; r++) sa[cf][r] = __expf(sa[cf][r] - mreg[r]);
#pragma unroll
    for (int r = 0; r < 4; r++) {
      float sv = sa[0][r] + sa[1][r] + sa[2][r] + sa[3][r];
#pragma unroll
      for (int off = 1; off < 16; off <<= 1) sv += __shfl_xor(sv, off);
      lreg[r] = lreg[r] * f[r] + sv;
    }
    // rescale O accumulator
#pragma unroll
    for (int cfc = 0; cfc < 16; cfc++)
#pragma unroll
      for (int r = 0; r < 4; r++) acc[cfc][r] *= f[r];

    // P -> LDS (wave-private rows; intra-wave RAW, no barrier)
#pragma unroll
    for (int cf = 0; cf < 4; cf++)
#pragma unroll
      for (int r = 0; r < 4; r++)
        Pt[w * 16 + g4 * 4 + r][cf * 16 + l16] = f2b(sa[cf][r]);

    // PV: A = P strip (row=l16), B = V[c][m]
#pragma unroll
    for (int kk = 0; kk < 2; kk++) {
      short8 pf = *(const short8*)&Pt[w * 16 + l16][kk * 32 + g4 * 8];
#pragma unroll
      for (int cfc = 0; cfc < 16; cfc++) {
        short8 vf = *(const short8*)&Vt[cfc * 16 + l16][kk * 32 + g4 * 8];
        acc[cfc] = mfma16(pf, vf, acc[cfc]);
      }
    }
  }

  // epilogue: unnormalized bf16 partials + stats
  unsigned short* poS = po + (size_t)s * N_DIM * C_DIM;
#pragma unroll
  for (int cfc = 0; cfc < 16; cfc++)
#pragma unroll
    for (int r = 0; r < 4; r++) {
      int n = n0 + w * 16 + g4 * 4 + r;
      int c = cfc * 16 + l16;
      poS[(size_t)n * C_DIM + c] = f2b(acc[cfc][r]);
    }
  if (l16 == 0) {
#pragma unroll
    for (int r = 0; r < 4; r++) {
      int n = n0 + w * 16 + g4 * 4 + r;
      m_arr[s * N_DIM + n] = mreg[r];
      l_arr[s * N_DIM + n] = lreg[r];
    }
  }
}

// ---------------- k5: combine 4 splits, transpose to [C][N], gamma ----------------
__global__ void k5_combine(const unsigned short* __restrict__ po, const float* __restrict__ m_arr,
                           const float* __restrict__ l_arr, const float* __restrict__ gamma,
                           float* __restrict__ out) {
  __shared__ float TT[64][65];
  int b = blockIdx.x;
  int c0 = (b & 3) * 64;
  int n0 = (b >> 2) * 64;
  float g = gamma[0];
  int tid = threadIdx.x;
#pragma unroll
  for (int rr = 0; rr < 16; rr++) {
    int idx = rr * 256 + tid;
    int nl = idx >> 6, cl = idx & 63;
    int n = n0 + nl;
    float m0v = m_arr[n], m1v = m_arr[N_DIM + n];
    float m2v = m_arr[2 * N_DIM + n], m3v = m_arr[3 * N_DIM + n];
    float M = fmaxf(fmaxf(m0v, m1v), fmaxf(m2v, m3v));
    float w0 = __expf(m0v - M), w1 = __expf(m1v - M);
    float w2 = __expf(m2v - M), w3 = __expf(m3v - M);
    float denom = l_arr[n] * w0 + l_arr[N_DIM + n] * w1 +
                  l_arr[2 * N_DIM + n] * w2 + l_arr[3 * N_DIM + n] * w3;
    float v0 = b2f(po[(size_t)n * C_DIM + c0 + cl]);
    float v1 = b2f(po[((size_t)N_DIM + n) * C_DIM + c0 + cl]);
    float v2 = b2f(po[((size_t)2 * N_DIM + n) * C_DIM + c0 + cl]);
    float v3 = b2f(po[((size_t)3 * N_DIM + n) * C_DIM + c0 + cl]);
    TT[cl][nl] = (v0 * w0 + v1 * w1 + v2 * w2 + v3 * w3) / denom;
  }
  __syncthreads();
#pragma unroll
  for (int rr = 0; rr < 16; rr++) {
    int idx = rr * 256 + tid;
    int cl = idx >> 6, nl = idx & 63;
    out[(size_t)(c0 + cl) * N_DIM + n0 + nl] = g * TT[cl][nl];
  }
}

// ---------------- launch ----------------
extern "C" void kernel_launch(void* const* d_in, const int* in_sizes, int n_in,
                              void* d_out, int out_size, void* d_ws, size_t ws_size,
                              hipStream_t stream) {
  const float* x  = (const float*)d_in[0];
  const float* y  = (const float*)d_in[1];
  const float* Wv = (const float*)d_in[2];
  const float* Wq = (const float*)d_in[3];
  const float* Wk = (const float*)d_in[5];
  const float* gamma = (const float*)d_in[7];
  float* out = (float*)d_out;

  char* ws = (char*)d_ws;
  constexpr size_t OFF_XMEAN = 0;
  constexpr size_t OFF_YMEAN = 1024;
  constexpr size_t OFF_QMEAN = 2048;
  constexpr size_t OFF_KMEAN = 2560;
  constexpr size_t OFF_XB    = 4096;
  constexpr size_t OFF_YB    = OFF_XB + 4718592;
  constexpr size_t OFF_WVB   = OFF_YB + 4718592;
  constexpr size_t OFF_WQB   = OFF_WVB + 131072;
  constexpr size_t OFF_WKB   = OFF_WQB + 32768;
  constexpr size_t OFF_QB    = OFF_WKB + 32768;
  constexpr size_t OFF_KB    = OFF_QB + 1179648;
  constexpr size_t OFF_VB    = OFF_KB + 1179648;
  constexpr size_t OFF_PO    = OFF_VB + 4718592;                 // 4 splits bf16
  constexpr size_t OFF_M     = OFF_PO + (size_t)SPLITS * N_DIM * C_DIM * 2;
  constexpr size_t OFF_L     = OFF_M + (size_t)SPLITS * N_DIM * 4;  // total ~36 MB

  float* xmean = (float*)(ws + OFF_XMEAN);
  float* ymean = (float*)(ws + OFF_YMEAN);
  float* qmean = (float*)(ws + OFF_QMEAN);
  float* kmean = (float*)(ws + OFF_KMEAN);
  unsigned short* xb  = (unsigned short*)(ws + OFF_XB);
  unsigned short* yb  = (unsigned short*)(ws + OFF_YB);
  unsigned short* Wvb = (unsigned short*)(ws + OFF_WVB);
  unsigned short* Wqb = (unsigned short*)(ws + OFF_WQB);
  unsigned short* Wkb = (unsigned short*)(ws + OFF_WKB);
  unsigned short* Qb  = (unsigned short*)(ws + OFF_QB);
  unsigned short* Kb  = (unsigned short*)(ws + OFF_KB);
  unsigned short* Vb  = (unsigned short*)(ws + OFF_VB);
  unsigned short* po  = (unsigned short*)(ws + OFF_PO);
  float* m_arr = (float*)(ws + OFF_M);
  float* l_arr = (float*)(ws + OFF_L);

  k1_mean_conv<<<512, 256, 0, stream>>>(x, y, xb, yb, xmean, ymean);
  k2_wconv<<<385, 256, 0, stream>>>(Wv, Wq, Wk, xmean, ymean, Wvb, Wqb, Wkb, qmean, kmean);
  k3_proj<<<432, 256, 0, stream>>>(xb, yb, Wvb, Wqb, Wkb, qmean, kmean, Qb, Kb, Vb);
  k4_attn<<<NT * SPLITS, 256, 0, stream>>>(Qb, Kb, Vb, po, m_arr, l_arr);
  k5_combine<<<576, 256, 0, stream>>>(po, m_arr, l_arr, gamma, out);
}